// Round 8
// baseline (188.307 us; speedup 1.0000x reference)
//
#include <hip/hip_runtime.h>
#include <hip/hip_bf16.h>

#define NB 8
#define NQ 8192
#define MP 2048
#define CDW 256
#define CSK 128
#define CIN 384
#define COUT 256

typedef __bf16 bf16_t;
typedef bf16_t bf16x8 __attribute__((ext_vector_type(8)));
typedef float f32x4 __attribute__((ext_vector_type(4)));

static __device__ __forceinline__ float bf2f(unsigned short u){
  union { unsigned int ui; float f; } v; v.ui = ((unsigned int)u) << 16; return v.f;
}
static __device__ __forceinline__ unsigned short f2bf(float f){
  union { float f; unsigned int u; } v; v.f = f;
  unsigned int u = v.u;
  return (unsigned short)((u + 0x7FFFu + ((u >> 16) & 1u)) >> 16);
}

// ---------------- weight conversion ----------------
__global__ void k_cvt_w(const float* __restrict__ W1, const float* __restrict__ W2,
                        unsigned short* __restrict__ W1b, unsigned short* __restrict__ W2b){
  int i = blockIdx.x * 256 + threadIdx.x;
  if (i < COUT*CIN) W1b[i] = f2bf(W1[i]);
  if (i < COUT*COUT) W2b[i] = f2bf(W2[i]);
}

// ---------------- Z = W1a * features_down : (B, M, 256) bf16, o-contiguous ----------------
__global__ __launch_bounds__(256) void k_z(const unsigned short* __restrict__ W1b,
    const float* __restrict__ fd, unsigned short* __restrict__ Z){
  __shared__ unsigned short Bl[64][264]; // [m][c], pad 8
  int b = blockIdx.y, m0 = blockIdx.x << 6;
  int t = threadIdx.x;
  {
    int m = t & 63, cs0 = t >> 6;
    for (int it = 0; it < 64; ++it){
      int c = cs0 + (it << 2);
      Bl[m][c] = f2bf(fd[((size_t)b*CDW + c)*MP + m0 + m]);
    }
  }
  __syncthreads();
  int l = t & 63, wv = t >> 6;
  int lr = l & 15, lg = l >> 4;
  int ob = wv << 6;
  f32x4 acc[4][4];
  #pragma unroll
  for (int i = 0; i < 4; ++i)
    #pragma unroll
    for (int j = 0; j < 4; ++j)
      acc[i][j] = (f32x4){0.f, 0.f, 0.f, 0.f};
  #pragma unroll 1
  for (int kt = 0; kt < 8; ++kt){
    int k0 = (kt << 5) + (lg << 3);
    bf16x8 af[4], bv[4];
    #pragma unroll
    for (int of = 0; of < 4; ++of)
      af[of] = *(const bf16x8*)(W1b + (size_t)(ob + (of<<4) + lr)*CIN + k0); // cols 0..255
    #pragma unroll
    for (int nf = 0; nf < 4; ++nf)
      bv[nf] = *(const bf16x8*)&Bl[(nf<<4) + lr][k0];
    #pragma unroll
    for (int of = 0; of < 4; ++of)
      #pragma unroll
      for (int nf = 0; nf < 4; ++nf)
        acc[of][nf] = __builtin_amdgcn_mfma_f32_16x16x32_bf16(af[of], bv[nf], acc[of][nf], 0, 0, 0);
  }
  #pragma unroll
  for (int of = 0; of < 4; ++of){
    int o = ob + (of<<4) + (lg<<2);
    #pragma unroll
    for (int nf = 0; nf < 4; ++nf){
      int m = m0 + (nf<<4) + lr;
      ushort4 pk;
      pk.x = f2bf(acc[of][nf][0]);
      pk.y = f2bf(acc[of][nf][1]);
      pk.z = f2bf(acc[of][nf][2]);
      pk.w = f2bf(acc[of][nf][3]);
      *(ushort4*)(Z + (((size_t)b*MP + m) << 8) + o) = pk;
    }
  }
}

// ---------------- 3-NN partial (M chunked), dual-query interleaved asm insert ----------------
#define CHUNKS 8
#define MC (MP/CHUNKS)

// Two independent top-3 chains (a,b) interleaved ABAB; 33 VALU per point for 2 queries.
// Each chain: 3 fma, 3 cmp, 10 cndmask. Masks: 2 SGPR pairs per chain. Shared mi.
#define NN_STEP2(P)                                                          \
  asm("v_fma_f32 %[sa], %[qxa], %[px], %[pw]\n\t"                            \
      "v_fma_f32 %[sb], %[qxb], %[px], %[pw]\n\t"                            \
      "v_fma_f32 %[sa], %[qya], %[py], %[sa]\n\t"                            \
      "v_fma_f32 %[sb], %[qyb], %[py], %[sb]\n\t"                            \
      "v_fma_f32 %[sa], %[qza], %[pz], %[sa]\n\t"                            \
      "v_fma_f32 %[sb], %[qzb], %[pz], %[sb]\n\t"                            \
      "v_cmp_gt_f32 %[m1a], %[sa], %[s1a]\n\t"                               \
      "v_cmp_gt_f32 %[m1b], %[sb], %[s1b]\n\t"                               \
      "v_cmp_gt_f32 %[m2a], %[sa], %[s2a]\n\t"                               \
      "v_cmp_gt_f32 %[m2b], %[sb], %[s2b]\n\t"                               \
      "v_cndmask_b32 %[s2a], %[s2a], %[sa], %[m2a]\n\t"                      \
      "v_cndmask_b32 %[s2b], %[s2b], %[sb], %[m2b]\n\t"                      \
      "v_cndmask_b32 %[i2a], %[i2a], %[mi], %[m2a]\n\t"                      \
      "v_cndmask_b32 %[i2b], %[i2b], %[mi], %[m2b]\n\t"                      \
      "v_cndmask_b32 %[s2a], %[s2a], %[s1a], %[m1a]\n\t"                     \
      "v_cndmask_b32 %[s2b], %[s2b], %[s1b], %[m1b]\n\t"                     \
      "v_cndmask_b32 %[i2a], %[i2a], %[i1a], %[m1a]\n\t"                     \
      "v_cndmask_b32 %[i2b], %[i2b], %[i1b], %[m1b]\n\t"                     \
      "v_cmp_gt_f32 %[m2a], %[sa], %[s0a]\n\t"                               \
      "v_cmp_gt_f32 %[m2b], %[sb], %[s0b]\n\t"                               \
      "v_cndmask_b32 %[s1a], %[s1a], %[sa], %[m1a]\n\t"                      \
      "v_cndmask_b32 %[s1b], %[s1b], %[sb], %[m1b]\n\t"                      \
      "v_cndmask_b32 %[i1a], %[i1a], %[mi], %[m1a]\n\t"                      \
      "v_cndmask_b32 %[i1b], %[i1b], %[mi], %[m1b]\n\t"                      \
      "v_cndmask_b32 %[s1a], %[s1a], %[s0a], %[m2a]\n\t"                     \
      "v_cndmask_b32 %[s1b], %[s1b], %[s0b], %[m2b]\n\t"                     \
      "v_cndmask_b32 %[i1a], %[i1a], %[i0a], %[m2a]\n\t"                     \
      "v_cndmask_b32 %[i1b], %[i1b], %[i0b], %[m2b]\n\t"                     \
      "v_cndmask_b32 %[s0a], %[s0a], %[sa], %[m2a]\n\t"                      \
      "v_cndmask_b32 %[s0b], %[s0b], %[sb], %[m2b]\n\t"                      \
      "v_cndmask_b32 %[i0a], %[i0a], %[mi], %[m2a]\n\t"                      \
      "v_cndmask_b32 %[i0b], %[i0b], %[mi], %[m2b]\n\t"                      \
      "v_add_u32 %[mi], 1, %[mi]\n\t"                                        \
      : [sa]"=&v"(sva), [sb]"=&v"(svb),                                      \
        [m1a]"=&s"(mk1a), [m2a]"=&s"(mk2a), [m1b]"=&s"(mk1b), [m2b]"=&s"(mk2b),\
        [s0a]"+v"(s0a), [s1a]"+v"(s1a), [s2a]"+v"(s2a),                      \
        [i0a]"+v"(i0a), [i1a]"+v"(i1a), [i2a]"+v"(i2a),                      \
        [s0b]"+v"(s0b), [s1b]"+v"(s1b), [s2b]"+v"(s2b),                      \
        [i0b]"+v"(i0b), [i1b]"+v"(i1b), [i2b]"+v"(i2b), [mi]"+v"(mi)         \
      : [qxa]"v"(qxa), [qya]"v"(qya), [qza]"v"(qza),                         \
        [qxb]"v"(qxb), [qyb]"v"(qyb), [qzb]"v"(qzb),                         \
        [px]"v"((P).x), [py]"v"((P).y), [pz]"v"((P).z), [pw]"v"((P).w))

__global__ __launch_bounds__(256, 2) void k_nn_part(const float* __restrict__ xu, const float* __restrict__ xd,
                                                    float* __restrict__ pd, int* __restrict__ pi){
  int b = blockIdx.z, ch = blockIdx.y, nt = blockIdx.x;
  int t = threadIdx.x;
  __shared__ float4 pts[MC];
  const float* xdb = xd + ((size_t)b*MP + (size_t)ch*MC)*3;
  if (t < MC){
    int p = t;
    float x = xdb[p*3+0], y = xdb[p*3+1], z = xdb[p*3+2];
    pts[p] = make_float4(x, y, z, -0.5f*(x*x + y*y + z*z));
  }
  __syncthreads();
  int na = nt*512 + t;
  int nb_ = na + 256;
  const float* qa = xu + ((size_t)b*NQ + na)*3;
  const float* qb = xu + ((size_t)b*NQ + nb_)*3;
  float qxa = qa[0], qya = qa[1], qza = qa[2];
  float qxb = qb[0], qyb = qb[1], qzb = qb[2];
  float qsa = qxa*qxa + qya*qya + qza*qza;
  float qsb = qxb*qxb + qyb*qyb + qzb*qzb;
  float s0a = -3.4e38f, s1a = -3.4e38f, s2a = -3.4e38f;
  float s0b = -3.4e38f, s1b = -3.4e38f, s2b = -3.4e38f;
  int i0a = 0, i1a = 0, i2a = 0, i0b = 0, i1b = 0, i2b = 0;
  int mi = 0;
  float sva, svb;
  unsigned long long mk1a, mk2a, mk1b, mk2b;
  #pragma unroll 1
  for (int mb = 0; mb < MC; mb += 8){
    float4 P0 = pts[mb+0], P1 = pts[mb+1], P2 = pts[mb+2], P3 = pts[mb+3];
    float4 P4 = pts[mb+4], P5 = pts[mb+5], P6 = pts[mb+6], P7 = pts[mb+7];
    NN_STEP2(P0); NN_STEP2(P1); NN_STEP2(P2); NN_STEP2(P3);
    NN_STEP2(P4); NN_STEP2(P5); NN_STEP2(P6); NN_STEP2(P7);
  }
  int gb = ch*MC;
  size_t basea = (((size_t)b*CHUNKS + ch)*NQ + na)*3;
  pd[basea+0] = qsa - 2.f*s0a; pd[basea+1] = qsa - 2.f*s1a; pd[basea+2] = qsa - 2.f*s2a;
  pi[basea+0] = gb + i0a; pi[basea+1] = gb + i1a; pi[basea+2] = gb + i2a;
  size_t baseb = (((size_t)b*CHUNKS + ch)*NQ + nb_)*3;
  pd[baseb+0] = qsb - 2.f*s0b; pd[baseb+1] = qsb - 2.f*s1b; pd[baseb+2] = qsb - 2.f*s2b;
  pi[baseb+0] = gb + i0b; pi[baseb+1] = gb + i1b; pi[baseb+2] = gb + i2b;
}

// ---------------- merge chunks -> idx + normalized weights ----------------
__global__ void k_nn_merge(const float* __restrict__ pd, const int* __restrict__ pi,
                           int* __restrict__ idx3, float* __restrict__ w3){
  int gid = blockIdx.x * 256 + threadIdx.x; // b*NQ + n
  int b = gid >> 13, n = gid & (NQ-1);
  float d0 = 3.4e38f, d1 = 3.4e38f, d2 = 3.4e38f;
  int i0 = 0, i1 = 0, i2 = 0;
  for (int ch = 0; ch < CHUNKS; ++ch){
    size_t base = (((size_t)b*CHUNKS + ch)*NQ + n)*3;
    #pragma unroll
    for (int k = 0; k < 3; ++k){
      float d = pd[base + k]; int gm = pi[base + k];
      bool c0 = d < d0, c1 = d < d1, c2 = d < d2;
      d2 = c1 ? d1 : (c2 ? d : d2);  i2 = c1 ? i1 : (c2 ? gm : i2);
      d1 = c0 ? d0 : (c1 ? d : d1);  i1 = c0 ? i0 : (c1 ? gm : i1);
      d0 = c0 ? d : d0;              i0 = c0 ? gm : i0;
    }
  }
  float w0 = 1.f / fmaxf(d0, 1e-10f);
  float w1 = 1.f / fmaxf(d1, 1e-10f);
  float w2 = 1.f / fmaxf(d2, 1e-10f);
  float s = w0 + w1 + w2;
  idx3[gid*3+0] = i0; idx3[gid*3+1] = i1; idx3[gid*3+2] = i2;
  w3[gid*3+0] = w0/s; w3[gid*3+1] = w1/s; w3[gid*3+2] = w2/s;
}

// ---------------- fused: Y1 = W1b*fu (GEMM K=128) + gather-sum(Z), partial BN stats ----------------
__global__ __launch_bounds__(256) void k_fused1(const unsigned short* __restrict__ W1b,
    const float* __restrict__ fu, const int* __restrict__ idx3, const float* __restrict__ w3,
    const unsigned short* __restrict__ Z,
    unsigned short* __restrict__ Y1, float* __restrict__ Sp, float* __restrict__ SSp){
  __shared__ unsigned short Xl[64][136]; // [n][c], 128 + 8 pad
  int tile = blockIdx.x;
  int b = tile >> 7;
  int n0 = (tile & 127) << 6;
  int t = threadIdx.x;
  {
    int n = t & 63, cs0 = t >> 6;
    for (int it = 0; it < 32; ++it){
      int cs = cs0 + (it << 2);
      Xl[n][cs] = f2bf(fu[((size_t)b*CSK + cs)*NQ + n0 + n]);
    }
  }
  __syncthreads();
  int l = t & 63, wv = t >> 6;
  int lr = l & 15, lg = l >> 4;
  int ob = wv << 6;
  f32x4 acc[4][4];
  #pragma unroll
  for (int i = 0; i < 4; ++i)
    #pragma unroll
    for (int j = 0; j < 4; ++j)
      acc[i][j] = (f32x4){0.f, 0.f, 0.f, 0.f};
  #pragma unroll 1
  for (int kt = 0; kt < 4; ++kt){
    int k0 = (kt << 5) + (lg << 3);
    bf16x8 af[4], bv[4];
    #pragma unroll
    for (int of = 0; of < 4; ++of)
      af[of] = *(const bf16x8*)(W1b + (size_t)(ob + (of<<4) + lr)*CIN + 256 + k0); // skip cols
    #pragma unroll
    for (int nf = 0; nf < 4; ++nf)
      bv[nf] = *(const bf16x8*)&Xl[(nf<<4) + lr][k0];
    #pragma unroll
    for (int of = 0; of < 4; ++of)
      #pragma unroll
      for (int nf = 0; nf < 4; ++nf)
        acc[of][nf] = __builtin_amdgcn_mfma_f32_16x16x32_bf16(af[of], bv[nf], acc[of][nf], 0, 0, 0);
  }
  // gather-add interp part: acc[of][nf][r] += sum_k w_k * Z[idx_k][o]
  const unsigned short* Zb = Z + (((size_t)b*MP) << 8);
  #pragma unroll
  for (int nf = 0; nf < 4; ++nf){
    int nn = n0 + (nf<<4) + lr;
    int q = ((b << 13) + nn) * 3;
    int j0 = idx3[q], j1 = idx3[q+1], j2 = idx3[q+2];
    float w0 = w3[q], w1 = w3[q+1], w2 = w3[q+2];
    const unsigned short* z0p = Zb + ((size_t)j0 << 8);
    const unsigned short* z1p = Zb + ((size_t)j1 << 8);
    const unsigned short* z2p = Zb + ((size_t)j2 << 8);
    #pragma unroll
    for (int of = 0; of < 4; ++of){
      int o = ob + (of<<4) + (lg<<2);
      ushort4 z0 = *(const ushort4*)(z0p + o);
      ushort4 z1 = *(const ushort4*)(z1p + o);
      ushort4 z2 = *(const ushort4*)(z2p + o);
      acc[of][nf][0] += w0*bf2f(z0.x) + w1*bf2f(z1.x) + w2*bf2f(z2.x);
      acc[of][nf][1] += w0*bf2f(z0.y) + w1*bf2f(z1.y) + w2*bf2f(z2.y);
      acc[of][nf][2] += w0*bf2f(z0.z) + w1*bf2f(z1.z) + w2*bf2f(z2.z);
      acc[of][nf][3] += w0*bf2f(z0.w) + w1*bf2f(z1.w) + w2*bf2f(z2.w);
    }
  }
  #pragma unroll
  for (int of = 0; of < 4; ++of){
    int o = ob + (of<<4) + (lg<<2);
    #pragma unroll
    for (int nf = 0; nf < 4; ++nf){
      int n = n0 + (nf<<4) + lr;
      size_t pos = ((size_t)b << 13) + n;
      ushort4 pk;
      pk.x = f2bf(acc[of][nf][0]);
      pk.y = f2bf(acc[of][nf][1]);
      pk.z = f2bf(acc[of][nf][2]);
      pk.w = f2bf(acc[of][nf][3]);
      *(ushort4*)(Y1 + pos*COUT + o) = pk;
    }
  }
  #pragma unroll
  for (int of = 0; of < 4; ++of){
    #pragma unroll
    for (int r = 0; r < 4; ++r){
      float sv = acc[of][0][r] + acc[of][1][r] + acc[of][2][r] + acc[of][3][r];
      float sq = acc[of][0][r]*acc[of][0][r] + acc[of][1][r]*acc[of][1][r]
               + acc[of][2][r]*acc[of][2][r] + acc[of][3][r]*acc[of][3][r];
      #pragma unroll
      for (int off = 1; off < 16; off <<= 1){
        sv += __shfl_xor(sv, off);
        sq += __shfl_xor(sq, off);
      }
      if (lr == 0){
        int o = ob + (of<<4) + (lg<<2) + r;
        Sp[(size_t)tile*256 + o] = sv;
        SSp[(size_t)tile*256 + o] = sq;
      }
    }
  }
}

// ---------------- reduce 1024 tile-partials -> per-channel sums ----------------
__global__ __launch_bounds__(256) void k_reduce(const float* __restrict__ Sp, const float* __restrict__ SSp,
                                                float* __restrict__ Sr, float* __restrict__ SSr){
  int t = threadIdx.x;
  int w = blockIdx.x * 4 + (t >> 6);   // 0..511
  int lane = t & 63;
  const float* src = (w < 256) ? Sp : SSp;
  int o = w & 255;
  float s = 0.f;
  #pragma unroll
  for (int j = 0; j < 16; ++j)
    s += src[(size_t)(lane + (j << 6))*256 + o];
  #pragma unroll
  for (int off = 1; off < 64; off <<= 1) s += __shfl_xor(s, off);
  if (lane == 0){
    if (w < 256) Sr[o] = s; else SSr[o] = s;
  }
}

// ---------------- BN finalize ----------------
__global__ void k_finalize(const float* __restrict__ S, const float* __restrict__ SS,
                           const float* __restrict__ g, const float* __restrict__ be,
                           float* __restrict__ scale, float* __restrict__ shift){
  int o = threadIdx.x;
  const float cnt = 65536.f;
  float mean = S[o] / cnt;
  float var = SS[o] / cnt - mean*mean;
  float inv = rsqrtf(var + 1e-5f);
  float sc = g[o] * inv;
  scale[o] = sc;
  shift[o] = be[o] - mean * sc;
}

// ---------------- GEMM2: Y2 = W2 * relu(BN(Y1)), partial BN stats, transposed output ----------------
__global__ __launch_bounds__(256) void k_gemm2(const unsigned short* __restrict__ W2b,
    const unsigned short* __restrict__ Y1, const float* __restrict__ scale1,
    const float* __restrict__ shift1, unsigned short* __restrict__ Y2,
    float* __restrict__ Sp, float* __restrict__ SSp){
  __shared__ unsigned short buf[256*68]; // phase1: Xl[64][264]; phase2: T[256][68]
  int tile = blockIdx.x;
  int b = tile >> 7;
  int n0 = (tile & 127) << 6;
  int t = threadIdx.x;
  {
    int nn0 = t >> 6;
    int cb = (t & 63) << 2;
    float scl[4], shl[4];
    #pragma unroll
    for (int j = 0; j < 4; ++j){ scl[j] = scale1[cb+j]; shl[j] = shift1[cb+j]; }
    for (int it = 0; it < 16; ++it){
      int nn = nn0 + (it << 2);
      size_t pos = ((size_t)b << 13) + n0 + nn;
      ushort4 a = *(const ushort4*)(Y1 + pos*COUT + cb);
      ushort4 r;
      r.x = f2bf(fmaxf(bf2f(a.x)*scl[0] + shl[0], 0.f));
      r.y = f2bf(fmaxf(bf2f(a.y)*scl[1] + shl[1], 0.f));
      r.z = f2bf(fmaxf(bf2f(a.z)*scl[2] + shl[2], 0.f));
      r.w = f2bf(fmaxf(bf2f(a.w)*scl[3] + shl[3], 0.f));
      *(ushort4*)&buf[nn*264 + cb] = r;
    }
  }
  __syncthreads();
  int l = t & 63, wv = t >> 6;
  int lr = l & 15, lg = l >> 4;
  int ob = wv << 6;
  f32x4 acc[4][4];
  #pragma unroll
  for (int i = 0; i < 4; ++i)
    #pragma unroll
    for (int j = 0; j < 4; ++j)
      acc[i][j] = (f32x4){0.f, 0.f, 0.f, 0.f};
  #pragma unroll 1
  for (int kt = 0; kt < 8; ++kt){
    int k0 = (kt << 5) + (lg << 3);
    bf16x8 af[4], bv[4];
    #pragma unroll
    for (int of = 0; of < 4; ++of)
      af[of] = *(const bf16x8*)(W2b + (size_t)(ob + (of<<4) + lr)*COUT + k0);
    #pragma unroll
    for (int nf = 0; nf < 4; ++nf)
      bv[nf] = *(const bf16x8*)&buf[((nf<<4) + lr)*264 + k0];
    #pragma unroll
    for (int of = 0; of < 4; ++of)
      #pragma unroll
      for (int nf = 0; nf < 4; ++nf)
        acc[of][nf] = __builtin_amdgcn_mfma_f32_16x16x32_bf16(af[of], bv[nf], acc[of][nf], 0, 0, 0);
  }
  // stats (pre-rounding, fp32)
  #pragma unroll
  for (int of = 0; of < 4; ++of){
    #pragma unroll
    for (int r = 0; r < 4; ++r){
      float sv = acc[of][0][r] + acc[of][1][r] + acc[of][2][r] + acc[of][3][r];
      float sq = acc[of][0][r]*acc[of][0][r] + acc[of][1][r]*acc[of][1][r]
               + acc[of][2][r]*acc[of][2][r] + acc[of][3][r]*acc[of][3][r];
      #pragma unroll
      for (int off = 1; off < 16; off <<= 1){
        sv += __shfl_xor(sv, off);
        sq += __shfl_xor(sq, off);
      }
      if (lr == 0){
        int o = ob + (of<<4) + (lg<<2) + r;
        Sp[(size_t)tile*256 + o] = sv;
        SSp[(size_t)tile*256 + o] = sq;
      }
    }
  }
  __syncthreads(); // all LDS reads done -> safe to overwrite as T
  #pragma unroll
  for (int of = 0; of < 4; ++of){
    int o = ob + (of<<4) + (lg<<2);
    #pragma unroll
    for (int nf = 0; nf < 4; ++nf){
      int n = (nf<<4) + lr;
      #pragma unroll
      for (int r = 0; r < 4; ++r)
        buf[(o + r)*68 + n] = f2bf(acc[of][nf][r]);
    }
  }
  __syncthreads();
  {
    int nx = (t & 31) << 1;
    int og = t >> 5;
    for (int it = 0; it < 32; ++it){
      int o = og + (it << 3);
      unsigned int v = (unsigned int)buf[o*68 + nx] | ((unsigned int)buf[o*68 + nx + 1] << 16);
      *(unsigned int*)(Y2 + (((size_t)b*COUT + o) << 13) + n0 + nx) = v;
    }
  }
}

// ---------------- final BN+ReLU -> fp32 out ----------------
__global__ void k_out(const unsigned short* __restrict__ Y2,
                      const float* __restrict__ scale2, const float* __restrict__ shift2,
                      float* __restrict__ out){
  size_t i = (size_t)blockIdx.x * 256 + threadIdx.x;
  size_t e = i << 2;
  int o = (int)((e >> 13) & 255);
  ushort4 v = *(const ushort4*)(Y2 + e);
  float sc = scale2[o], sh = shift2[o];
  float4 r;
  r.x = fmaxf(bf2f(v.x)*sc + sh, 0.f);
  r.y = fmaxf(bf2f(v.y)*sc + sh, 0.f);
  r.z = fmaxf(bf2f(v.z)*sc + sh, 0.f);
  r.w = fmaxf(bf2f(v.w)*sc + sh, 0.f);
  *(float4*)(out + e) = r;
}

extern "C" void kernel_launch(void* const* d_in, const int* in_sizes, int n_in,
                              void* d_out, int out_size, void* d_ws, size_t ws_size,
                              hipStream_t stream) {
  (void)in_sizes; (void)n_in; (void)out_size; (void)ws_size;
  const float* xu = (const float*)d_in[0];
  const float* xd = (const float*)d_in[1];
  const float* fu = (const float*)d_in[2];
  const float* fd = (const float*)d_in[3];
  const float* W1 = (const float*)d_in[4];
  const float* g1 = (const float*)d_in[5];
  const float* b1 = (const float*)d_in[6];
  const float* W2 = (const float*)d_in[7];
  const float* g2 = (const float*)d_in[8];
  const float* b2 = (const float*)d_in[9];
  float* out = (float*)d_out;

  char* w = (char*)d_ws;
  size_t off = 0;
  unsigned short* Z   = (unsigned short*)(w + off); off += (size_t)NB*MP*256*2;      // 8 MB
  unsigned short* W1b = (unsigned short*)(w + off); off += (size_t)COUT*CIN*2;
  unsigned short* W2b = (unsigned short*)(w + off); off += (size_t)COUT*COUT*2;
  float* pd  = (float*)(w + off); off += (size_t)NB*CHUNKS*NQ*3*4;
  int*   pi  = (int*)(w + off);   off += (size_t)NB*CHUNKS*NQ*3*4;
  int*   idx3= (int*)(w + off);   off += (size_t)NB*NQ*3*4;
  float* w3  = (float*)(w + off); off += (size_t)NB*NQ*3*4;
  unsigned short* Y1 = (unsigned short*)(w + off); off += (size_t)NB*NQ*COUT*2;      // 32 MB
  unsigned short* Y2 = (unsigned short*)(w + off); off += (size_t)NB*NQ*COUT*2;      // 32 MB
  float* Sp1  = (float*)(w + off); off += (size_t)1024*256*4;                        // 1 MB
  float* SSp1 = (float*)(w + off); off += (size_t)1024*256*4;
  float* Sp2  = (float*)(w + off); off += (size_t)1024*256*4;
  float* SSp2 = (float*)(w + off); off += (size_t)1024*256*4;
  float* Sr1  = (float*)(w + off); off += 256*4;
  float* SSr1 = (float*)(w + off); off += 256*4;
  float* Sr2  = (float*)(w + off); off += 256*4;
  float* SSr2 = (float*)(w + off); off += 256*4;
  float* scale1 = (float*)(w + off); off += 256*4;
  float* shift1 = (float*)(w + off); off += 256*4;
  float* scale2 = (float*)(w + off); off += 256*4;
  float* shift2 = (float*)(w + off); off += 256*4;

  k_cvt_w<<<dim3(384), dim3(256), 0, stream>>>(W1, W2, W1b, W2b);
  k_z<<<dim3(32, 8), dim3(256), 0, stream>>>(W1b, fd, Z);
  k_nn_part<<<dim3(16, 8, 8), dim3(256), 0, stream>>>(xu, xd, pd, pi);
  k_nn_merge<<<dim3(256), dim3(256), 0, stream>>>(pd, pi, idx3, w3);
  k_fused1<<<dim3(1024), dim3(256), 0, stream>>>(W1b, fu, idx3, w3, Z, Y1, Sp1, SSp1);
  k_reduce<<<dim3(128), dim3(256), 0, stream>>>(Sp1, SSp1, Sr1, SSr1);
  k_finalize<<<dim3(1), dim3(256), 0, stream>>>(Sr1, SSr1, g1, b1, scale1, shift1);
  k_gemm2<<<dim3(1024), dim3(256), 0, stream>>>(W2b, Y1, scale1, shift1, Y2, Sp2, SSp2);
  k_reduce<<<dim3(128), dim3(256), 0, stream>>>(Sp2, SSp2, Sr2, SSr2);
  k_finalize<<<dim3(1), dim3(256), 0, stream>>>(Sr2, SSr2, g2, b2, scale2, shift2);
  k_out<<<dim3(16384), dim3(256), 0, stream>>>(Y2, scale2, shift2, out);
}